// Round 5
// baseline (413.171 us; speedup 1.0000x reference)
//
#include <hip/hip_runtime.h>

constexpr int B      = 4;
constexpr int T      = 4096;
constexpr int C      = 64;                 // input dim
constexpr int H      = 64;                 // head dim
constexpr int TILE   = 32;                 // query rows per block
constexpr int HALO   = 2;                  // window radius
constexpr int HR     = TILE + 2 * HALO;    // 36 halo rows
constexpr int LS     = 68;                 // LDS row stride (floats): float4-aligned, rotates banks by 4/row
constexpr int NT     = 256;
constexpr int NTILES = T / TILE;           // 128

typedef float f32x4 __attribute__((ext_vector_type(4)));

// Pure streaming zero-fill of the attn region, replicating the rocclr
// fillBufferAligned pattern (256 thr, tiny VGPR, contiguous float4 stores,
// grid-stride). Harness evidence: this pattern runs at 6.1 TB/s with ZERO
// RMW fetch on this very buffer. hipMemsetAsync in a captured graph was
// ~1.3 TB/s (r4) — do not use it.
__global__ __launch_bounds__(256)
void fill_attn_zero(f32x4* __restrict__ dst, size_t n4)
{
    const size_t stride = (size_t)gridDim.x * 256;
    const f32x4 z = (f32x4)0.f;
    for (size_t i = (size_t)blockIdx.x * 256 + threadIdx.x; i < n4; i += stride)
        dst[i] = z;
}

// Writes ONLY op + the <=2 aligned float4 band groups per attn row
// (~5 MB total). Bulk zeros come from fill_attn_zero (stream-ordered
// before us; dispatch-boundary release/acquire makes them visible).
__global__ __launch_bounds__(NT, 2)
void sparse_attn_fused(const float* __restrict__ x,
                       const float* __restrict__ Wq,
                       const float* __restrict__ Wk,
                       const float* __restrict__ Wv,
                       float* __restrict__ out)
{
    __shared__ float sX[HR][LS];       // x halo rows
    __shared__ float sQ[TILE][LS];
    __shared__ float sK[HR][LS];
    __shared__ float sV[HR][LS];
    __shared__ float sS[TILE][8];      // scores, then probs (5 used per row)

    const int tid  = threadIdx.x;
    const int b    = blockIdx.x / NTILES;
    const int tile = blockIdx.x % NTILES;
    const int row0 = tile * TILE;
    const float* xb = x + (size_t)b * T * C;

    // ---- stage x halo rows into LDS (zero-padded at batch edges) ----
    for (int s = tid; s < HR * (C / 4); s += NT) {
        const int lr = s >> 4;
        const int c4 = (s & 15) << 2;
        const int gr = row0 + lr - HALO;
        float4 v = make_float4(0.f, 0.f, 0.f, 0.f);
        if (gr >= 0 && gr < T) v = *(const float4*)(xb + (size_t)gr * C + c4);
        *(float4*)&sX[lr][c4] = v;
    }

    const int h = tid & 63;      // head-dim column this lane owns
    const int w = tid >> 6;      // wave id 0..3

    // W row for this lane in registers (16 KB per matrix, L2-resident across 512 blocks)
    float4 wr[16];
#pragma unroll
    for (int c4 = 0; c4 < 16; ++c4) wr[c4] = *(const float4*)(Wq + h * C + c4 * 4);

    __syncthreads();

    // ---- Q = X[tile] @ Wq^T : wave w computes rows w*8..w*8+7; sX row broadcast ----
#pragma unroll
    for (int ii = 0; ii < 8; ++ii) {
        const int i = w * 8 + ii;
        float acc = 0.f;
#pragma unroll
        for (int c4 = 0; c4 < 16; ++c4) {
            const float4 xv = *(const float4*)&sX[i + HALO][c4 * 4];
            acc = fmaf(xv.x, wr[c4].x, acc);
            acc = fmaf(xv.y, wr[c4].y, acc);
            acc = fmaf(xv.z, wr[c4].z, acc);
            acc = fmaf(xv.w, wr[c4].w, acc);
        }
        sQ[i][h] = acc;
    }

    // ---- K = X[halo] @ Wk^T : wave w computes rows w*9..w*9+8 ----
#pragma unroll
    for (int c4 = 0; c4 < 16; ++c4) wr[c4] = *(const float4*)(Wk + h * C + c4 * 4);
#pragma unroll
    for (int ii = 0; ii < 9; ++ii) {
        const int l = w * 9 + ii;
        float acc = 0.f;
#pragma unroll
        for (int c4 = 0; c4 < 16; ++c4) {
            const float4 xv = *(const float4*)&sX[l][c4 * 4];
            acc = fmaf(xv.x, wr[c4].x, acc);
            acc = fmaf(xv.y, wr[c4].y, acc);
            acc = fmaf(xv.z, wr[c4].z, acc);
            acc = fmaf(xv.w, wr[c4].w, acc);
        }
        sK[l][h] = acc;
    }

    // ---- V = X[halo] @ Wv^T ----
#pragma unroll
    for (int c4 = 0; c4 < 16; ++c4) wr[c4] = *(const float4*)(Wv + h * C + c4 * 4);
#pragma unroll
    for (int ii = 0; ii < 9; ++ii) {
        const int l = w * 9 + ii;
        float acc = 0.f;
#pragma unroll
        for (int c4 = 0; c4 < 16; ++c4) {
            const float4 xv = *(const float4*)&sX[l][c4 * 4];
            acc = fmaf(xv.x, wr[c4].x, acc);
            acc = fmaf(xv.y, wr[c4].y, acc);
            acc = fmaf(xv.z, wr[c4].z, acc);
            acc = fmaf(xv.w, wr[c4].w, acc);
        }
        sV[l][h] = acc;
    }

    __syncthreads();

    // ---- scores: 32 rows x 5 offsets on 160 threads ----
    if (tid < TILE * 5) {
        const int i  = tid / 5;
        const int dj = tid % 5;
        const int jg = row0 + i - HALO + dj;
        float sc = -__builtin_inff();
        if (jg >= 0 && jg < T) {
            float acc = 0.f;
#pragma unroll
            for (int c4 = 0; c4 < C; c4 += 4) {
                const float4 q = *(const float4*)&sQ[i][c4];
                const float4 k = *(const float4*)&sK[i + dj][c4];
                acc = fmaf(q.x, k.x, acc);
                acc = fmaf(q.y, k.y, acc);
                acc = fmaf(q.z, k.z, acc);
                acc = fmaf(q.w, k.w, acc);
            }
            // scale = C^-0.5 = 0.125 ; +1 bias inside band for j > i (dj > 2), per triu(ones,1)
            sc = acc * 0.125f + (dj > 2 ? 1.0f : 0.0f);
        }
        sS[i][dj] = sc;
    }
    __syncthreads();

    // ---- softmax per row; write the <=2 aligned float4 band groups directly ----
    const size_t attnBase = (size_t)B * T * H;
    if (tid < TILE) {
        const int i  = tid;
        const int ig = row0 + i;
        float sc[5];
        float m = -__builtin_inff();
#pragma unroll
        for (int d = 0; d < 5; ++d) { sc[d] = sS[i][d]; m = fmaxf(m, sc[d]); }
        float p[5];
        float sum = 0.f;
#pragma unroll
        for (int d = 0; d < 5; ++d) { p[d] = expf(sc[d] - m); sum += p[d]; }
        const float inv = 1.f / sum;

        const int j0   = ig - HALO;
        const int G0   = (j0 > 0 ? j0 : 0) >> 2;     // first touched float4 group
        const int base = G0 << 2;
        float bw[8];
#pragma unroll
        for (int q = 0; q < 8; ++q) bw[q] = 0.f;
#pragma unroll
        for (int d = 0; d < 5; ++d) {
            const float pv = p[d] * inv;             // exp(-inf)=0 -> prob 0 for invalid j
            sS[i][d] = pv;
            const int off = j0 + d - base;
            if (off >= 0 && off < 8) bw[off] = pv;   // j>=T slots carry prob 0, harmless
        }
        f32x4* drow = (f32x4*)(out + attnBase + ((size_t)b * T + ig) * T);
        f32x4 v0; v0.x = bw[0]; v0.y = bw[1]; v0.z = bw[2]; v0.w = bw[3];
        drow[G0] = v0;
        if (G0 + 1 < T / 4) {                        // top edge: window tail is all zeros
            f32x4 v1; v1.x = bw[4]; v1.y = bw[5]; v1.z = bw[6]; v1.w = bw[7];
            drow[G0 + 1] = v1;                       // (fill already zeroed; skip avoids
        }                                            //  racing the next batch's row 0)
    }
    __syncthreads();

    // ---- op = P @ V : 512 float4 outputs, coalesced ----
    for (int s = tid; s < TILE * (H / 4); s += NT) {
        const int r  = s >> 4;
        const int hq = (s & 15) << 2;
        float4 acc = make_float4(0.f, 0.f, 0.f, 0.f);
#pragma unroll
        for (int d = 0; d < 5; ++d) {
            const float pv = sS[r][d];
            const float4 vv = *(const float4*)&sV[r + d][hq];
            acc.x = fmaf(pv, vv.x, acc.x);
            acc.y = fmaf(pv, vv.y, acc.y);
            acc.z = fmaf(pv, vv.z, acc.z);
            acc.w = fmaf(pv, vv.w, acc.w);
        }
        *(float4*)(out + ((size_t)b * T + row0 + r) * H + hq) = acc;
    }
}

extern "C" void kernel_launch(void* const* d_in, const int* in_sizes, int n_in,
                              void* d_out, int out_size, void* d_ws, size_t ws_size,
                              hipStream_t stream) {
    (void)in_sizes; (void)n_in; (void)d_ws; (void)ws_size; (void)out_size;
    const float* x  = (const float*)d_in[0];
    const float* Wq = (const float*)d_in[1];
    const float* Wk = (const float*)d_in[2];
    const float* Wv = (const float*)d_in[3];
    float* out = (float*)d_out;

    // Zero the dense attn region with our own shader fill (6.1 TB/s pattern,
    // zero RMW fetch — harness fillBufferAligned evidence). Stream order
    // makes it complete before sparse_attn_fused's band stores.
    f32x4* attn4 = (f32x4*)(out + (size_t)B * T * H);
    const size_t n4 = (size_t)B * T * T / 4;        // 16,777,216 float4s
    fill_attn_zero<<<dim3(8192), dim3(256), 0, stream>>>(attn4, n4);

    sparse_attn_fused<<<dim3(B * NTILES), dim3(NT), 0, stream>>>(x, Wq, Wk, Wv, out);
}